// Round 6
// baseline (171.615 us; speedup 1.0000x reference)
//
#include <hip/hip_runtime.h>
#include <cstdint>
#include <cstddef>

typedef unsigned short u16;
typedef u16   u16x8  __attribute__((ext_vector_type(8)));
typedef u16   u16x4  __attribute__((ext_vector_type(4)));
typedef __bf16 bf16x8 __attribute__((ext_vector_type(8)));
typedef float f32x4  __attribute__((ext_vector_type(4)));
typedef float f32x2  __attribute__((ext_vector_type(2)));

__device__ __forceinline__ float bf2f(u16 v) {
  unsigned int u = ((unsigned int)v) << 16;
  return __builtin_bit_cast(float, u);
}
__device__ __forceinline__ u16 f2bf(float f) {
  unsigned int x = __builtin_bit_cast(unsigned int, f);
  x += 0x7fffu + ((x >> 16) & 1u);   // RNE
  return (u16)(x >> 16);
}

// ---------------------------------------------------------------------------
// Kernel 1 (fat): blocks 0..255   -> transpose W21/W22 f32 -> bf16 Wt [n][k]
//                 blocks 256..8447-> h1 = relu(x @ W1 + b1) (RAW x) -> bf16,
//                                    and zero head[row][0..3] (ws is poisoned)
// ---------------------------------------------------------------------------
__global__ __launch_bounds__(256) void k_prep(const float* __restrict__ W21,
                                              const float* __restrict__ W22,
                                              u16* __restrict__ Wt,
                                              const float* __restrict__ x,
                                              const float* __restrict__ W1,
                                              const float* __restrict__ b1,
                                              u16* __restrict__ h1,
                                              float* __restrict__ head) {
  __shared__ u16 s[64][65];
  const int b = blockIdx.x;
  if (b < 256) {
    const int mat = b >> 7;
    const int tt  = b & 127;
    const int k0  = (tt >> 3) * 64;
    const int n0  = (tt & 7) * 64;
    const float* W = mat ? W22 : W21;
    const int tx = threadIdx.x & 63;
    const int ty = threadIdx.x >> 6;
#pragma unroll
    for (int i = 0; i < 16; ++i) {
      int r = i * 4 + ty;
      s[r][tx] = f2bf(W[(size_t)(k0 + r) * 512 + n0 + tx]);
    }
    __syncthreads();
    const int nbase = mat * 512 + n0;
#pragma unroll
    for (int i = 0; i < 16; ++i) {
      int r = i * 4 + ty;
      Wt[(size_t)(nbase + r) * 1024 + k0 + tx] = s[tx][r];
    }
  } else {
    const int row = b - 256;
    if (threadIdx.x == 0)
      *(f32x4*)(head + 4 * (size_t)row) = f32x4{0.f, 0.f, 0.f, 0.f};
    const int c4 = threadIdx.x * 4;
    const float* xr = x + (size_t)row * 8;
    f32x4 acc = *(const f32x4*)(b1 + c4);
#pragma unroll
    for (int f = 0; f < 8; ++f) {
      float xv = xr[f];                     // row-uniform -> scalar loads
      f32x4 wv = *(const f32x4*)(W1 + f * 1024 + c4);
#pragma unroll
      for (int e = 0; e < 4; ++e) acc[e] = fmaf(xv, wv[e], acc[e]);
    }
    u16x4 o;
#pragma unroll
    for (int e = 0; e < 4; ++e) o[e] = f2bf(fmaxf(acc[e], 0.f));
    *(u16x4*)(h1 + (size_t)row * 1024 + c4) = o;
  }
}

// ---------------------------------------------------------------------------
// Kernel 2: GEMM + fused head epilogue.
// X2-tile = relu(h1 @ [W21|W22] + bias) stays in registers (fp32); each block
// dots it against W31/W32 column slices and atomicAdds 128x2 partials into
// head[8192][4]. X2 is never materialized.
// ---------------------------------------------------------------------------
__global__ __launch_bounds__(256) void k_gemm(const u16* __restrict__ A,
                                              const u16* __restrict__ Bt,
                                              const float* __restrict__ b21,
                                              const float* __restrict__ b22,
                                              const float* __restrict__ W31,
                                              const float* __restrict__ W32,
                                              float* __restrict__ head) {
  constexpr int K  = 1024;
  constexpr int BK = 32;
  constexpr int NT = K / BK;          // 32 K-tiles
  __shared__ u16 As[2][128 * BK];
  __shared__ u16 Bs[2][128 * BK];

  const int t    = threadIdx.x;
  const int row0 = blockIdx.y * 128;
  const int col0 = blockIdx.x * 128;
  const int w    = t >> 6;
  const int lane = t & 63;
  const int wr   = w >> 1, wc = w & 1;      // 2x2 wave grid, 64x64 per wave
  const int lrow = lane & 15;
  const int lk   = (lane >> 4) * 8;

  const int c0 = t, c1 = 256 + t;           // chunk: row=c>>2, kchunk=c&3
  const u16* gA0 = A  + (size_t)(row0 + (c0 >> 2)) * K + (c0 & 3) * 8;
  const u16* gA1 = A  + (size_t)(row0 + (c1 >> 2)) * K + (c1 & 3) * 8;
  const u16* gB0 = Bt + (size_t)(col0 + (c0 >> 2)) * K + (c0 & 3) * 8;
  const u16* gB1 = Bt + (size_t)(col0 + (c1 >> 2)) * K + (c1 & 3) * 8;
  const int lo0 = c0 * 8, lo1 = c1 * 8;

  f32x4 acc[4][4];
#pragma unroll
  for (int i = 0; i < 4; ++i)
#pragma unroll
    for (int j = 0; j < 4; ++j) acc[i][j] = f32x4{0.f, 0.f, 0.f, 0.f};

  {
    u16x8 ta0 = *(const u16x8*)gA0;
    u16x8 ta1 = *(const u16x8*)gA1;
    u16x8 tb0 = *(const u16x8*)gB0;
    u16x8 tb1 = *(const u16x8*)gB1;
    *(u16x8*)(As[0] + lo0) = ta0;
    *(u16x8*)(As[0] + lo1) = ta1;
    *(u16x8*)(Bs[0] + lo0) = tb0;
    *(u16x8*)(Bs[0] + lo1) = tb1;
  }
  u16x8 na0 = *(const u16x8*)(gA0 + BK);
  u16x8 na1 = *(const u16x8*)(gA1 + BK);
  u16x8 nb0 = *(const u16x8*)(gB0 + BK);
  u16x8 nb1 = *(const u16x8*)(gB1 + BK);

  for (int kt = 0; kt < NT; ++kt) {
    const int cur = kt & 1, nxt = cur ^ 1;
    __syncthreads();

    const int koff = (kt + 2 < NT ? kt + 2 : NT - 1) * BK;
    u16x8 fa0 = *(const u16x8*)(gA0 + koff);
    u16x8 fa1 = *(const u16x8*)(gA1 + koff);
    u16x8 fb0 = *(const u16x8*)(gB0 + koff);
    u16x8 fb1 = *(const u16x8*)(gB1 + koff);

    bf16x8 af[4], bfr[4];
#pragma unroll
    for (int i = 0; i < 4; ++i)
      af[i] = __builtin_bit_cast(bf16x8,
          *(const u16x8*)(As[cur] + (wr * 64 + i * 16 + lrow) * BK + lk));
#pragma unroll
    for (int j = 0; j < 4; ++j)
      bfr[j] = __builtin_bit_cast(bf16x8,
          *(const u16x8*)(Bs[cur] + (wc * 64 + j * 16 + lrow) * BK + lk));
#pragma unroll
    for (int i = 0; i < 4; ++i)
#pragma unroll
      for (int j = 0; j < 4; ++j)
        acc[i][j] = __builtin_amdgcn_mfma_f32_16x16x32_bf16(af[i], bfr[j], acc[i][j], 0, 0, 0);

    if (kt + 1 < NT) {
      *(u16x8*)(As[nxt] + lo0) = na0;
      *(u16x8*)(As[nxt] + lo1) = na1;
      *(u16x8*)(Bs[nxt] + lo0) = nb0;
      *(u16x8*)(Bs[nxt] + lo1) = nb1;
    }
    na0 = fa0; na1 = fa1; nb0 = fb0; nb1 = fb1;
  }

  // ---- fused head epilogue ----
  // acc[i][j][rr]: row = row0+wr*64+i*16+(lane>>4)*4+rr, col = col0+wc*64+j*16+lrow
  const bool isX21 = (col0 < 512);
  const float* Wh  = isX21 ? W31 : W32;      // [512][2] row-major
  const int   hoff = isX21 ? 0 : 2;

  float hx[16], hy[16];
#pragma unroll
  for (int n = 0; n < 16; ++n) { hx[n] = 0.f; hy[n] = 0.f; }
#pragma unroll
  for (int j = 0; j < 4; ++j) {
    int col  = col0 + wc * 64 + j * 16 + lrow;
    int wcol = col & 511;
    f32x2 wv = *(const f32x2*)(Wh + 2 * wcol);
    float bias = isX21 ? b21[col] : b22[wcol];
#pragma unroll
    for (int i = 0; i < 4; ++i)
#pragma unroll
      for (int rr = 0; rr < 4; ++rr) {
        float v = fmaxf(acc[i][j][rr] + bias, 0.f);
        hx[i * 4 + rr] = fmaf(v, wv[0], hx[i * 4 + rr]);
        hy[i * 4 + rr] = fmaf(v, wv[1], hy[i * 4 + rr]);
      }
  }
  // reduce across the 16 col-lanes (masks 1,2,4,8 stay inside the group)
#pragma unroll
  for (int m = 1; m <= 8; m <<= 1) {
#pragma unroll
    for (int n = 0; n < 16; ++n) {
      hx[n] += __shfl_xor(hx[n], m, 64);
      hy[n] += __shfl_xor(hy[n], m, 64);
    }
  }
  if (lrow == 0) {
    const int rq = (lane >> 4) * 4;
#pragma unroll
    for (int i = 0; i < 4; ++i)
#pragma unroll
      for (int rr = 0; rr < 4; ++rr) {
        int row = row0 + wr * 64 + i * 16 + rq + rr;
        atomicAdd(head + 4 * (size_t)row + hoff,     hx[i * 4 + rr]);
        atomicAdd(head + 4 * (size_t)row + hoff + 1, hy[i * 4 + rr]);
      }
  }
}

// ---------------------------------------------------------------------------
// Kernel 3: rank-2 dual PGD QP. One thread per row; heads precomputed.
// ---------------------------------------------------------------------------
__global__ __launch_bounds__(256) void k_qp(const float* __restrict__ x,
                                            const float* __restrict__ mean_,
                                            const float* __restrict__ std_,
                                            const float* __restrict__ head,
                                            const float* __restrict__ b31,
                                            const float* __restrict__ b32,
                                            const float* __restrict__ obstacles,
                                            float* __restrict__ out) {
  const int r = blockIdx.x * 256 + threadIdx.x;
  f32x4 hd = *(const f32x4*)(head + 4 * (size_t)r);
  float p0  = hd[0] + b31[0];
  float p1v = hd[1] + b31[1];
  float pp1 = 4.f / (1.f + expf(-(hd[2] + b32[0])));
  float pp2 = 4.f / (1.f + expf(-(hd[3] + b32[1])));

  const f32x4* xp = (const f32x4*)(x + (size_t)r * 8);
  f32x4 xa = xp[0], xb = xp[1];
  float px = xa[0] * std_[0] + mean_[0];
  float py = xa[1] * std_[1] + mean_[1];
  float th = xa[2] * std_[2] + mean_[2];
  float v  = xa[3] * std_[3] + mean_[3];
  float ax = xb[0] * std_[4] + mean_[4];
  float ay = xb[1] * std_[5] + mean_[5];
  float st = sinf(th), ct = cosf(th);
  float Lf2b = 2.f * v * v;

  float G0[9], G1[9], q[9];
  float s00 = 0.f, s01 = 0.f, s11 = 0.f;
#pragma unroll
  for (int m = 0; m < 9; ++m) {
    float ox, oy, orad;
    if (m < 8) {
      ox = obstacles[m * 3]; oy = obstacles[m * 3 + 1]; orad = obstacles[m * 3 + 2];
    } else { ox = ax; oy = ay; orad = 0.5f; }
    float R  = 0.6f + orad;                  // AGENT_RADIUS + orad + SAFETY
    float dx = px - ox, dy = py - oy;
    float bar  = dx * dx + dy * dy - R * R;
    float dct  = dx * ct + dy * st;
    float bdot = 2.f * v * dct;
    float g0 = 2.f * v * (dx * st - dy * ct);   // -LgLfbu1
    float g1 = -2.f * dct;                      // -LgLfbu2
    float h  = Lf2b + (pp1 + pp2) * bdot + pp1 * pp2 * bar;
    G0[m] = g0; G1[m] = g1;
    q[m] = g0 * p0 + g1 * p1v + h;
    s00 += g0 * g0; s01 += g0 * g1; s11 += g1 * g1;
  }
  float L = sqrtf(s00 * s00 + 2.f * s01 * s01 + s11 * s11) + 1e-6f;
  float alpha = 1.f / L;

  float lam[9];
#pragma unroll
  for (int m = 0; m < 9; ++m) lam[m] = 0.f;
  for (int it = 0; it < 300; ++it) {
    float pr0[9], pr1[9];
#pragma unroll
    for (int m = 0; m < 9; ++m) { pr0[m] = G0[m] * lam[m]; pr1[m] = G1[m] * lam[m]; }
    float t0 = (((pr0[0] + pr0[1]) + (pr0[2] + pr0[3])) +
                ((pr0[4] + pr0[5]) + (pr0[6] + pr0[7]))) + pr0[8];
    float t1 = (((pr1[0] + pr1[1]) + (pr1[2] + pr1[3])) +
                ((pr1[4] + pr1[5]) + (pr1[6] + pr1[7]))) + pr1[8];
#pragma unroll
    for (int m = 0; m < 9; ++m) {
      float g = fmaf(G0[m], t0, fmaf(G1[m], t1, q[m]));
      lam[m] = fmaxf(fmaf(-alpha, g, lam[m]), 0.f);
    }
  }
  float u0 = -p0, u1 = -p1v;
#pragma unroll
  for (int m = 0; m < 9; ++m) { u0 = fmaf(-G0[m], lam[m], u0); u1 = fmaf(-G1[m], lam[m], u1); }
  *(f32x2*)(out + 2 * (size_t)r) = f32x2{u0, u1};
}

// ---------------------------------------------------------------------------
extern "C" void kernel_launch(void* const* d_in, const int* in_sizes, int n_in,
                              void* d_out, int out_size, void* d_ws, size_t ws_size,
                              hipStream_t stream) {
  const float* x    = (const float*)d_in[0];
  const float* mean_= (const float*)d_in[1];
  const float* std_ = (const float*)d_in[2];
  const float* W1   = (const float*)d_in[3];
  const float* b1   = (const float*)d_in[4];
  const float* W21  = (const float*)d_in[5];
  const float* b21  = (const float*)d_in[6];
  const float* W22  = (const float*)d_in[7];
  const float* b22  = (const float*)d_in[8];
  // d_in[9],[10] = W23,b23 : dead code in reference (x33 unused)
  const float* W31  = (const float*)d_in[11];
  const float* b31  = (const float*)d_in[12];
  const float* W32  = (const float*)d_in[13];
  const float* b32  = (const float*)d_in[14];
  // d_in[15],[16] = W33,b33 : dead code
  const float* obst = (const float*)d_in[17];
  float* out = (float*)d_out;

  char* ws = (char*)d_ws;
  u16*   Wt   = (u16*)ws;                                   // 2 MB
  u16*   h1   = (u16*)(ws + (size_t)(1 << 21));             // 16 MB
  float* head = (float*)(ws + (size_t)(1 << 21) + (size_t)(1 << 24)); // 128 KB

  k_prep<<<256 + 8192, 256, 0, stream>>>(W21, W22, Wt, x, W1, b1, h1, head);
  k_gemm<<<dim3(8, 64), 256, 0, stream>>>(h1, Wt, b21, b22, W31, W32, head);
  k_qp  <<<32, 256, 0, stream>>>(x, mean_, std_, head, b31, b32, obst, out);
}